// Round 8
// baseline (118.731 us; speedup 1.0000x reference)
//
#include <hip/hip_runtime.h>
#include <hip/hip_bf16.h>

#define B_DIM 512
#define D_DIM 256
#define C_DIM 100000
#define LAMB 1000.0f
#define NPANEL 782            // ceil(C/128)

using bf16x8 = __attribute__((ext_vector_type(8))) short;
using f32x4  = __attribute__((ext_vector_type(4))) float;

__device__ __forceinline__ short f2bf(float f) {
  unsigned u = __builtin_bit_cast(unsigned, f);
  u += 0x7FFFu + ((u >> 16) & 1u);      // round-to-nearest-even
  return (short)(u >> 16);
}

// async global->LDS, 16B per lane; LDS dest = wave-uniform base + lane*16
__device__ __forceinline__ void gload_lds16(const void* g, void* l) {
  __builtin_amdgcn_global_load_lds(
      (__attribute__((address_space(1))) void*)g,
      (__attribute__((address_space(3))) void*)l, 16, 0, 0);
}

// Kernel 1: xlen per row + bf16 x, pre-swizzled (byte ^= (row&7)<<4) so the
// GEMM's linear LDS staging + swizzled ds_read_b128 is bank-conflict-minimal.
__global__ __launch_bounds__(256) void prep_x(const float* __restrict__ x,
                                              unsigned short* __restrict__ x_swz,
                                              float* __restrict__ xlen) {
  int wv = threadIdx.x >> 6, lane = threadIdx.x & 63;
  int row = blockIdx.x * 4 + wv;
  float4 v = *(const float4*)(x + row * D_DIM + lane * 4);
  float ss = v.x * v.x + v.y * v.y + v.z * v.z + v.w * v.w;
#pragma unroll
  for (int m = 1; m < 64; m <<= 1) ss += __shfl_xor(ss, m);
  if (lane == 0) xlen[row] = sqrtf(ss);
  ushort4 u;
  u.x = (unsigned short)f2bf(v.x);
  u.y = (unsigned short)f2bf(v.y);
  u.z = (unsigned short)f2bf(v.z);
  u.w = (unsigned short)f2bf(v.w);
  int byteoff = row * 512 + ((lane * 8) ^ ((row & 7) << 4));
  *(ushort4*)((char*)x_swz + byteoff) = u;
}

// Kernel 2: GEMM, barrier-free main loop.
// Grid: 782 col-panels x 4 row-groups of 128 rows, decoded XCD-grouped
// (bid = xcd + 8*(rg + 4*pp)) so a panel's 4 row-group blocks run
// back-to-back on the SAME XCD -> W panel is fetched into that XCD's L2
// once and re-read 3x from L2 (W HBM/L3 traffic stays ~1x).
// Each block: stage 64KB x-slice into LDS ONCE (gload_lds, fire-and-forget),
// W panel -> register A-frags (r4-proven), ONE __syncthreads, then 8 j-tiles
// of ds_read/MFMA/float4-stores with no further syncs — waves free-run,
// store latency hides under the next tile. (r1/r4/r5 all pinned at ~88us on
// the 16-chunk barrier lockstep; this removes it.)
__global__ __launch_bounds__(256) void gemm_bf16(
    const float* __restrict__ W, const unsigned short* __restrict__ xb,
    const float* __restrict__ xlen, float* __restrict__ out) {
  __shared__ unsigned short xs[128 * 256];   // 64 KB x slice (swizzled rows)
  __shared__ float xlen_s[128];

  const int tid = threadIdx.x;
  const int lane = tid & 63, wv = tid >> 6;
  const int l15 = lane & 15, g = lane >> 4;

  const int bid = blockIdx.x;
  const int xcd = bid & 7, t = bid >> 3, rg = t & 3, pp = t >> 2;
  const int panel = pp * 8 + xcd;
  if (panel >= NPANEL) return;               // 8 pad blocks; before any barrier
  const int bn0 = panel * 128 + wv * 32;
  const int row0 = rg * 128;

  // stage the 128-row x slice (fire-and-forget; drained by the syncthreads)
  const char* xsrc = (const char*)xb + row0 * 512;
#pragma unroll
  for (int i = 0; i < 16; ++i)
    gload_lds16(xsrc + i * 4096 + tid * 16, (char*)xs + i * 4096 + wv * 1024);

  if (tid < 128) xlen_s[tid] = xlen[row0 + tid];

  // ---- Phase 1: W cols -> A-frags (bf16) + inv_wlen (fp32), r4-style ----
  // A-frag: lane holds A[row][k], row = lane&15 -> W-col, k = kg*32+g*8+j.
  bf16x8 fw[2][8];
  float invw4[2][4];   // inv_wlen for W-col = bn0 + it*16 + g*4 + r
#pragma unroll
  for (int it = 0; it < 2; ++it) {
    int col = bn0 + it * 16 + l15;
    if (col >= C_DIM) col = C_DIM - 1;        // clamp; stores are guarded
    const float* wr = W + (size_t)col * D_DIM + g * 8;
    float ss = 0.f;
#pragma unroll
    for (int kg = 0; kg < 8; ++kg) {
      float4 a = *(const float4*)(wr + kg * 32);
      float4 b = *(const float4*)(wr + kg * 32 + 4);
      ss += a.x * a.x + a.y * a.y + a.z * a.z + a.w * a.w
          + b.x * b.x + b.y * b.y + b.z * b.z + b.w * b.w;
      bf16x8 f;
      f[0] = f2bf(a.x); f[1] = f2bf(a.y); f[2] = f2bf(a.z); f[3] = f2bf(a.w);
      f[4] = f2bf(b.x); f[5] = f2bf(b.y); f[6] = f2bf(b.z); f[7] = f2bf(b.w);
      fw[it][kg] = f;
    }
    ss += __shfl_xor(ss, 16);                 // reduce across the 4 g-groups
    ss += __shfl_xor(ss, 32);
    float iw = 1.0f / sqrtf(ss);              // lane l15 holds col bn0+it*16+l15
#pragma unroll
    for (int r = 0; r < 4; ++r) invw4[it][r] = __shfl(iw, g * 4 + r);
  }

  __syncthreads();   // x slice staged + all waves ready; ONLY barrier

  // ---- Main loop: 8 j-tiles of 16 x-rows, barrier-free ----
#pragma unroll 2
  for (int jtl = 0; jtl < 8; ++jtl) {
    const int lr = jtl * 16 + l15;            // local x-row (B col = lane&15)
    const float xl = xlen_s[lr];
    const char* xp = (const char*)xs + lr * 512;
    const int swz = (l15 & 7) << 4;
    bf16x8 fx[8];
#pragma unroll
    for (int kg = 0; kg < 8; ++kg)
      fx[kg] = *(const bf16x8*)(xp + ((kg * 64 + g * 16) ^ swz));

    f32x4 acc0 = {}, acc1 = {};
#pragma unroll
    for (int kg = 0; kg < 8; ++kg) {
      acc0 = __builtin_amdgcn_mfma_f32_16x16x32_bf16(fw[0][kg], fx[kg], acc0, 0, 0, 0);
      acc1 = __builtin_amdgcn_mfma_f32_16x16x32_bf16(fw[1][kg], fx[kg], acc1, 0, 0, 0);
    }

    // epilogue: feat = clamp(dot * inv_wlen, -xlen, xlen); float4 stores
    const size_t orow = (size_t)(row0 + lr) * C_DIM;
#pragma unroll
    for (int it = 0; it < 2; ++it) {
      const f32x4& a = it ? acc1 : acc0;
      int wc = bn0 + it * 16 + g * 4;         // D row = g*4 + r -> W-col
      if (wc < C_DIM) {                       // C%4==0 -> float4 all-or-nothing
        float4 v;
        v.x = fminf(fmaxf(a[0] * invw4[it][0], -xl), xl);
        v.y = fminf(fmaxf(a[1] * invw4[it][1], -xl), xl);
        v.z = fminf(fmaxf(a[2] * invw4[it][2], -xl), xl);
        v.w = fminf(fmaxf(a[3] * invw4[it][3], -xl), xl);
        *(float4*)(out + orow + wc) = v;
      }
    }
  }
}

// Kernel 3: exact fp32 recompute of the 512 label positions (margin math).
__global__ __launch_bounds__(256) void fix_labels(const float* __restrict__ x,
                                                  const float* __restrict__ W,
                                                  const int* __restrict__ y,
                                                  float* __restrict__ out) {
  int wv = threadIdx.x >> 6, lane = threadIdx.x & 63;
  int b = blockIdx.x * 4 + wv;
  int c = y[b];
  float4 wvv = *(const float4*)(W + (size_t)c * D_DIM + lane * 4);
  float4 xv  = *(const float4*)(x + b * D_DIM + lane * 4);
  float dt = wvv.x * xv.x + wvv.y * xv.y + wvv.z * xv.z + wvv.w * xv.w;
  float sw = wvv.x * wvv.x + wvv.y * wvv.y + wvv.z * wvv.z + wvv.w * wvv.w;
  float sx = xv.x * xv.x + xv.y * xv.y + xv.z * xv.z + xv.w * xv.w;
#pragma unroll
  for (int m = 1; m < 64; m <<= 1) {
    dt += __shfl_xor(dt, m);
    sw += __shfl_xor(sw, m);
    sx += __shfl_xor(sx, m);
  }
  if (lane == 0) {
    float xl = sqrtf(sx), wl = sqrtf(sw);
    float cth = dt / (xl * wl);
    cth = fminf(fmaxf(cth, -1.f), 1.f);
    float c2 = cth * cth;
    float cm = 8.f * c2 * c2 - 8.f * c2 + 1.f;          // cos(4t) Chebyshev
    float k = floorf(4.0f * acosf(cth) / 3.14159265358979323846f);
    float sgn = (((int)k) & 1) ? -1.f : 1.f;
    float phi = sgn * cm - 2.f * k;
    float feat = cth * xl;
    out[(size_t)b * C_DIM + c] = feat + (phi * xl - feat) / (1.f + LAMB);
  }
}

extern "C" void kernel_launch(void* const* d_in, const int* in_sizes, int n_in,
                              void* d_out, int out_size, void* d_ws, size_t ws_size,
                              hipStream_t stream) {
  const float* x = (const float*)d_in[0];
  const float* W = (const float*)d_in[1];
  const int*   y = (const int*)d_in[2];
  float* out = (float*)d_out;

  unsigned short* xb = (unsigned short*)d_ws;                    // 256 KB (swizzled bf16 x)
  float* xlen = (float*)((char*)d_ws + B_DIM * D_DIM * 2);       // 2 KB

  prep_x<<<B_DIM / 4, 256, 0, stream>>>(x, xb, xlen);
  gemm_bf16<<<8 * 4 * 98, 256, 0, stream>>>(W, xb, xlen, out);   // 3136 blocks
  fix_labels<<<B_DIM / 4, 256, 0, stream>>>(x, W, y, out);
}

// Round 9
// 93.747 us; speedup vs baseline: 1.2665x; 1.2665x over previous
//
#include <hip/hip_runtime.h>
#include <hip/hip_bf16.h>

#define B_DIM 512
#define D_DIM 256
#define C_DIM 100000
#define LAMB 1000.0f

using bf16x8 = __attribute__((ext_vector_type(8))) short;
using f32x4  = __attribute__((ext_vector_type(4))) float;

__device__ __forceinline__ short f2bf(float f) {
  unsigned u = __builtin_bit_cast(unsigned, f);
  u += 0x7FFFu + ((u >> 16) & 1u);      // round-to-nearest-even
  return (short)(u >> 16);
}

// async global->LDS, 16B per lane; LDS dest = wave-uniform base + lane*16
__device__ __forceinline__ void gload_lds16(const void* g, void* l) {
  __builtin_amdgcn_global_load_lds(
      (__attribute__((address_space(1))) void*)g,
      (__attribute__((address_space(3))) void*)l, 16, 0, 0);
}

// Kernel 1: xlen per row + bf16 x, pre-swizzled (byte ^= (row&7)<<4) so the
// GEMM's linear LDS staging + swizzled ds_read_b128 is bank-conflict-minimal.
__global__ __launch_bounds__(256) void prep_x(const float* __restrict__ x,
                                              unsigned short* __restrict__ x_swz,
                                              float* __restrict__ xlen) {
  int wv = threadIdx.x >> 6, lane = threadIdx.x & 63;
  int row = blockIdx.x * 4 + wv;
  float4 v = *(const float4*)(x + row * D_DIM + lane * 4);
  float ss = v.x * v.x + v.y * v.y + v.z * v.z + v.w * v.w;
#pragma unroll
  for (int m = 1; m < 64; m <<= 1) ss += __shfl_xor(ss, m);
  if (lane == 0) xlen[row] = sqrtf(ss);
  ushort4 u;
  u.x = (unsigned short)f2bf(v.x);
  u.y = (unsigned short)f2bf(v.y);
  u.z = (unsigned short)f2bf(v.z);
  u.w = (unsigned short)f2bf(v.w);
  int byteoff = row * 512 + ((lane * 8) ^ ((row & 7) << 4));
  *(ushort4*)((char*)x_swz + byteoff) = u;
}

// Kernel 2: GEMM, r4 geometry (grid over N only, W read exactly once,
// 4 waves x 32 cols, 512 rows/block) + T3/T4 counted-vmcnt pipeline:
// 32 chunks of 16 rows, QUAD-buffered LDS (4 x 8KB), staging issued 2
// chunks ahead, raw s_barrier once per chunk, and a DERIVED vmcnt wait
// (never 0 in the loop): per wave per iter the VMEM order is
// [2 gload_lds (chunk k+2)] ... [2 stores (chunk k)], so at iter k the
// gloads of chunk k (issued at iter k-2) have exactly 8 newer VMEM ops
// -> s_waitcnt vmcnt(8). Edges: k=0/31 -> 4, k=1/30 -> 6.
// Buffer reuse is barrier-safe: A(k) overwrites buf[(k+2)&3], whose last
// reader was C(k-2); barrier B(k-1) separates them for all wave pairs.
__global__ __launch_bounds__(256) void gemm_bf16(
    const float* __restrict__ W, const unsigned short* __restrict__ xb,
    const float* __restrict__ xlen, float* __restrict__ out) {
  __shared__ unsigned short xs[4][16 * 256];   // 4 x 8 KB (swizzled rows)
  __shared__ float xlen_s[B_DIM];

  const int tid = threadIdx.x;
  const int lane = tid & 63, wv = tid >> 6;
  const int l15 = lane & 15, g = lane >> 4;
  const int bn0 = blockIdx.x * 128 + wv * 32;

  for (int i = tid; i < B_DIM; i += 256) xlen_s[i] = xlen[i];

  // prologue: stage chunks 0 and 1 (per wave: 2 gload_lds each)
#pragma unroll
  for (int c = 0; c < 2; ++c)
#pragma unroll
    for (int i = 0; i < 2; ++i)
      gload_lds16((const char*)xb + c * 8192 + wv * 2048 + i * 1024 + lane * 16,
                  (char*)xs[c] + wv * 2048 + i * 1024 + lane * 16);

  // ---- Phase 1: W cols -> A-frags (bf16) + inv_wlen (fp32), r4-proven ----
  // A-frag: lane holds A[row][k], row = lane&15 -> W-col, k = kg*32+g*8+j.
  // W raw loads are consumed here (compiler-inserted waits), so by the main
  // loop only the x gloads + stores are outstanding -> manual counts hold.
  bf16x8 fw[2][8];
  float invw4[2][4];   // inv_wlen for W-col = bn0 + it*16 + g*4 + r
#pragma unroll
  for (int it = 0; it < 2; ++it) {
    int col = bn0 + it * 16 + l15;
    if (col >= C_DIM) col = C_DIM - 1;        // clamp; stores are guarded
    const float* wr = W + (size_t)col * D_DIM + g * 8;
    float ss = 0.f;
#pragma unroll
    for (int kg = 0; kg < 8; ++kg) {
      float4 a = *(const float4*)(wr + kg * 32);
      float4 b = *(const float4*)(wr + kg * 32 + 4);
      ss += a.x * a.x + a.y * a.y + a.z * a.z + a.w * a.w
          + b.x * b.x + b.y * b.y + b.z * b.z + b.w * b.w;
      bf16x8 f;
      f[0] = f2bf(a.x); f[1] = f2bf(a.y); f[2] = f2bf(a.z); f[3] = f2bf(a.w);
      f[4] = f2bf(b.x); f[5] = f2bf(b.y); f[6] = f2bf(b.z); f[7] = f2bf(b.w);
      fw[it][kg] = f;
    }
    ss += __shfl_xor(ss, 16);                 // reduce across the 4 g-groups
    ss += __shfl_xor(ss, 32);
    float iw = 1.0f / sqrtf(ss);              // lane l15 holds col bn0+it*16+l15
#pragma unroll
    for (int r = 0; r < 4; ++r) invw4[it][r] = __shfl(iw, g * 4 + r);
  }

  // ---- Main loop: 32 chunks of 16 rows, counted-vmcnt pipeline ----
  for (int k = 0; k < 32; ++k) {
    // A: stage chunk k+2 into buf[(k+2)&3]
    if (k < 30) {
#pragma unroll
      for (int i = 0; i < 2; ++i)
        gload_lds16((const char*)xb + (k + 2) * 8192 + wv * 2048 + i * 1024 + lane * 16,
                    (char*)xs[(k + 2) & 3] + wv * 2048 + i * 1024 + lane * 16);
    }
    __builtin_amdgcn_sched_barrier(0);

    // B: derived wait (chunk k staged) + barrier; stores stay in flight
    if (k == 0 || k == 31)
      asm volatile("s_waitcnt vmcnt(4)" ::: "memory");
    else if (k == 1 || k == 30)
      asm volatile("s_waitcnt vmcnt(6)" ::: "memory");
    else
      asm volatile("s_waitcnt vmcnt(8)" ::: "memory");
    __builtin_amdgcn_s_barrier();
    __builtin_amdgcn_sched_barrier(0);

    // C: compute chunk k (16 rows x 128 cols)
    const int row = k * 16 + l15;             // B col = lane&15 -> x-row
    const float xl = xlen_s[row];
    const char* xp = (const char*)xs[k & 3] + l15 * 512;
    const int swz = (l15 & 7) << 4;
    bf16x8 fx[8];
#pragma unroll
    for (int kg = 0; kg < 8; ++kg)
      fx[kg] = *(const bf16x8*)(xp + ((kg * 64 + g * 16) ^ swz));

    f32x4 acc0 = {}, acc1 = {};
#pragma unroll
    for (int kg = 0; kg < 8; ++kg) {
      acc0 = __builtin_amdgcn_mfma_f32_16x16x32_bf16(fw[0][kg], fx[kg], acc0, 0, 0, 0);
      acc1 = __builtin_amdgcn_mfma_f32_16x16x32_bf16(fw[1][kg], fx[kg], acc1, 0, 0, 0);
    }

    // epilogue: feat = clamp(dot * inv_wlen, -xlen, xlen); float4 stores
    const size_t orow = (size_t)row * C_DIM;
#pragma unroll
    for (int it = 0; it < 2; ++it) {
      const f32x4& a = it ? acc1 : acc0;
      int wc = bn0 + it * 16 + g * 4;         // D row = g*4 + r -> W-col
      if (wc < C_DIM) {                       // C%4==0 -> float4 all-or-nothing
        float4 v;
        v.x = fminf(fmaxf(a[0] * invw4[it][0], -xl), xl);
        v.y = fminf(fmaxf(a[1] * invw4[it][1], -xl), xl);
        v.z = fminf(fmaxf(a[2] * invw4[it][2], -xl), xl);
        v.w = fminf(fmaxf(a[3] * invw4[it][3], -xl), xl);
        *(float4*)(out + orow + wc) = v;
      }
    }
  }
}

// Kernel 3: exact fp32 recompute of the 512 label positions (margin math).
__global__ __launch_bounds__(256) void fix_labels(const float* __restrict__ x,
                                                  const float* __restrict__ W,
                                                  const int* __restrict__ y,
                                                  float* __restrict__ out) {
  int wv = threadIdx.x >> 6, lane = threadIdx.x & 63;
  int b = blockIdx.x * 4 + wv;
  int c = y[b];
  float4 wvv = *(const float4*)(W + (size_t)c * D_DIM + lane * 4);
  float4 xv  = *(const float4*)(x + b * D_DIM + lane * 4);
  float dt = wvv.x * xv.x + wvv.y * xv.y + wvv.z * xv.z + wvv.w * xv.w;
  float sw = wvv.x * wvv.x + wvv.y * wvv.y + wvv.z * wvv.z + wvv.w * wvv.w;
  float sx = xv.x * xv.x + xv.y * xv.y + xv.z * xv.z + xv.w * xv.w;
#pragma unroll
  for (int m = 1; m < 64; m <<= 1) {
    dt += __shfl_xor(dt, m);
    sw += __shfl_xor(sw, m);
    sx += __shfl_xor(sx, m);
  }
  if (lane == 0) {
    float xl = sqrtf(sx), wl = sqrtf(sw);
    float cth = dt / (xl * wl);
    cth = fminf(fmaxf(cth, -1.f), 1.f);
    float c2 = cth * cth;
    float cm = 8.f * c2 * c2 - 8.f * c2 + 1.f;          // cos(4t) Chebyshev
    float k = floorf(4.0f * acosf(cth) / 3.14159265358979323846f);
    float sgn = (((int)k) & 1) ? -1.f : 1.f;
    float phi = sgn * cm - 2.f * k;
    float feat = cth * xl;
    out[(size_t)b * C_DIM + c] = feat + (phi * xl - feat) / (1.f + LAMB);
  }
}

extern "C" void kernel_launch(void* const* d_in, const int* in_sizes, int n_in,
                              void* d_out, int out_size, void* d_ws, size_t ws_size,
                              hipStream_t stream) {
  const float* x = (const float*)d_in[0];
  const float* W = (const float*)d_in[1];
  const int*   y = (const int*)d_in[2];
  float* out = (float*)d_out;

  unsigned short* xb = (unsigned short*)d_ws;                    // 256 KB (swizzled bf16 x)
  float* xlen = (float*)((char*)d_ws + B_DIM * D_DIM * 2);       // 2 KB

  prep_x<<<B_DIM / 4, 256, 0, stream>>>(x, xb, xlen);
  gemm_bf16<<<(C_DIM + 127) / 128, 256, 0, stream>>>(W, xb, xlen, out);
  fix_labels<<<B_DIM / 4, 256, 0, stream>>>(x, W, y, out);
}